// Round 3
// baseline (1436.846 us; speedup 1.0000x reference)
//
#include <hip/hip_runtime.h>
#include <hip/hip_bf16.h>

// GCN layer: out = D^-1/2 (A + I) D^-1/2 (x W^T + b)
// R3 pipeline (no exact CSR — bucket partition + LDS-accumulated spmm):
//   0. memset cnt[N] + tailB[B]    (contiguous, one memset)
//   1. k_part: per edge e: b=dst>>5; pos=atomicAdd(tailB[b]);
//              P[b*CAP+pos] = (src<<5)|(dst&31);  atomicAdd(cnt[dst])
//   2. k_rinv: rinv = rsqrt(cnt+1)
//   3. k_gemm: hs = bf16( rinv[r] * (x W^T + b) )
//   4. k_spmm_b: one WG per bucket (32 nodes): LDS tile[32][128] fp32
//              init = self term hs[node]; per edge: tile[dst&31][c] += hs[src][c]
//              (LDS atomic, 2-way bank alias = free); out = rinv[dst]*tile

#define N_NODES 100000
#define N_EDGES 1600000
#define CH 128
#define NB 3125          // buckets = N/32 exactly
#define CAP 1024         // bucket capacity; Poisson(512) -> 22 sigma headroom

__device__ inline unsigned short f2bf(float f) {          // RNE float->bf16
    unsigned u = __float_as_uint(f);
    u += 0x7fffu + ((u >> 16) & 1u);
    return (unsigned short)(u >> 16);
}
__device__ inline float bf2f(unsigned short s) {
    return __uint_as_float(((unsigned)s) << 16);
}

// ---------------- partition + degree histogram ----------------
__global__ __launch_bounds__(256) void k_part(const int* __restrict__ src,
                                              const int* __restrict__ dst,
                                              int* __restrict__ tailB,
                                              unsigned* __restrict__ P,
                                              int* __restrict__ cnt) {
    int e = blockIdx.x * 256 + threadIdx.x;   // grid exactly covers E
    int s = src[e];
    int d = dst[e];
    int b = d >> 5;
    int pos = atomicAdd(&tailB[b], 1);
    if (pos < CAP) P[(size_t)b * CAP + pos] = ((unsigned)s << 5) | (unsigned)(d & 31);
    atomicAdd(&cnt[d], 1);
}

// ---------------- rinv = 1/sqrt(deg+1) ----------------
__global__ __launch_bounds__(256) void k_rinv(const int* __restrict__ cnt,
                                              float* __restrict__ rinv) {
    int i = blockIdx.x * 256 + threadIdx.x;
    if (i < N_NODES) rinv[i] = rsqrtf((float)(cnt[i] + 1));
}

// ---------------- GEMM: hs = bf16( rinv * (x W^T + b) ) ----------------
// 32 rows x 128 cols per block, 256 threads, 4x4 micro-tile per thread.
__global__ __launch_bounds__(256) void k_gemm(const float* __restrict__ x,
                                              const float* __restrict__ W,
                                              const float* __restrict__ b,
                                              const float* __restrict__ rinv,
                                              unsigned short* __restrict__ hs) {
    __shared__ __align__(16) float xs[32][36];    // [row][kk]
    __shared__ __align__(16) float ws[32][132];   // [kk][o]
    const int t  = threadIdx.x;
    const int tx = t & 31;          // output cols o = 4*tx + c
    const int ty = t >> 5;          // rows r = ty + 8*i
    const int row0 = blockIdx.x * 32;

    float acc[4][4] = {};

    for (int k0 = 0; k0 < CH; k0 += 32) {
        {
            int r  = t >> 5;
            int kk = t & 31;
            for (int p = 0; p < 4; ++p) {
                int rr = r + p * 8;
                xs[rr][kk] = x[(size_t)(row0 + rr) * CH + k0 + kk];
            }
            int o = t >> 5;
            for (int p = 0; p < 16; ++p) {
                int oo = o + p * 8;
                ws[kk][oo] = W[(size_t)oo * CH + k0 + kk];
            }
        }
        __syncthreads();

        for (int k4 = 0; k4 < 32; k4 += 4) {
            float4 xv[4], wv[4];
            for (int i = 0; i < 4; ++i)
                xv[i] = *(const float4*)&xs[ty + 8 * i][k4];
            for (int j = 0; j < 4; ++j)
                wv[j] = *(const float4*)&ws[k4 + j][4 * tx];
            for (int i = 0; i < 4; ++i) {
                acc[i][0] += xv[i].x * wv[0].x; acc[i][1] += xv[i].x * wv[0].y;
                acc[i][2] += xv[i].x * wv[0].z; acc[i][3] += xv[i].x * wv[0].w;
                acc[i][0] += xv[i].y * wv[1].x; acc[i][1] += xv[i].y * wv[1].y;
                acc[i][2] += xv[i].y * wv[1].z; acc[i][3] += xv[i].y * wv[1].w;
                acc[i][0] += xv[i].z * wv[2].x; acc[i][1] += xv[i].z * wv[2].y;
                acc[i][2] += xv[i].z * wv[2].z; acc[i][3] += xv[i].z * wv[2].w;
                acc[i][0] += xv[i].w * wv[3].x; acc[i][1] += xv[i].w * wv[3].y;
                acc[i][2] += xv[i].w * wv[3].z; acc[i][3] += xv[i].w * wv[3].w;
            }
        }
        __syncthreads();
    }

    float4 bv = *(const float4*)&b[4 * tx];
    for (int i = 0; i < 4; ++i) {
        int r = row0 + ty + 8 * i;
        float ri = rinv[r];
        ushort4 o4;
        o4.x = f2bf(ri * (acc[i][0] + bv.x));
        o4.y = f2bf(ri * (acc[i][1] + bv.y));
        o4.z = f2bf(ri * (acc[i][2] + bv.z));
        o4.w = f2bf(ri * (acc[i][3] + bv.w));
        *(ushort4*)&hs[(size_t)r * CH + 4 * tx] = o4;
    }
}

// ---------------- bucketed SpMM with LDS accumulation ----------------
// One WG (256 thr) per bucket of 32 nodes. 2 edge-slots x 128 lanes.
// tile[r][c]: lane c -> bank c%32, 64-lane wave covers each bank 2x (free).
__global__ __launch_bounds__(256) void k_spmm_b(const unsigned* __restrict__ P,
                                                const int* __restrict__ tailB,
                                                const float* __restrict__ rinv,
                                                const unsigned short* __restrict__ hs,
                                                float* __restrict__ out) {
    __shared__ float tile[32][CH];                // 16 KB
    const int b     = blockIdx.x;
    const int node0 = b << 5;
    const int t     = threadIdx.x;

    // init with self term: tile[r][c] = hs[node0+r][c]
    for (int idx = t; idx < 32 * CH; idx += 256) {
        tile[idx >> 7][idx & 127] = bf2f(hs[((size_t)node0 << 7) + idx]);
    }
    int nE = tailB[b];
    if (nE > CAP) nE = CAP;
    __syncthreads();

    const int slot = t >> 7;          // 0 or 1
    const int lane = t & 127;         // channel
    const unsigned* Pb = P + (size_t)b * CAP;

    // split edges: slot 0 takes [0,half), slot 1 takes [half,nE) — sequential reads
    const int half  = (nE + 1) >> 1;
    const int begin = slot ? half : 0;
    const int end   = slot ? nE : half;

    int e = begin;
    for (; e + 4 <= end; e += 4) {
        unsigned p0 = Pb[e + 0];
        unsigned p1 = Pb[e + 1];
        unsigned p2 = Pb[e + 2];
        unsigned p3 = Pb[e + 3];
        float v0 = bf2f(hs[((size_t)(p0 >> 5) << 7) + lane]);
        float v1 = bf2f(hs[((size_t)(p1 >> 5) << 7) + lane]);
        float v2 = bf2f(hs[((size_t)(p2 >> 5) << 7) + lane]);
        float v3 = bf2f(hs[((size_t)(p3 >> 5) << 7) + lane]);
        atomicAdd(&tile[p0 & 31][lane], v0);
        atomicAdd(&tile[p1 & 31][lane], v1);
        atomicAdd(&tile[p2 & 31][lane], v2);
        atomicAdd(&tile[p3 & 31][lane], v3);
    }
    for (; e < end; ++e) {
        unsigned p = Pb[e];
        float v = bf2f(hs[((size_t)(p >> 5) << 7) + lane]);
        atomicAdd(&tile[p & 31][lane], v);
    }
    __syncthreads();

    // epilogue: out = rinv[dst] * tile, coalesced
    for (int idx = t; idx < 32 * CH; idx += 256) {
        int r = idx >> 7;
        out[((size_t)node0 << 7) + idx] = rinv[node0 + r] * tile[r][idx & 127];
    }
}

extern "C" void kernel_launch(void* const* d_in, const int* in_sizes, int n_in,
                              void* d_out, int out_size, void* d_ws, size_t ws_size,
                              hipStream_t stream) {
    const float* x  = (const float*)d_in[0];
    const int*   ei = (const int*)d_in[1];
    const float* W  = (const float*)d_in[2];
    const float* b  = (const float*)d_in[3];
    float* out = (float*)d_out;

    const int* src = ei;
    const int* dst = ei + N_EDGES;

    // workspace layout (4-byte units; every region multiple of 4 elems -> hs 16B-aligned)
    int*      cnt   = (int*)d_ws;                         // N      (100000)
    int*      tailB = cnt + N_NODES;                      // 4096   (NB used)
    float*    rinv  = (float*)(tailB + 4096);             // N
    unsigned* P     = (unsigned*)(rinv + N_NODES);        // NB*CAP = 3,200,000
    unsigned short* hs = (unsigned short*)(P + (size_t)NB * CAP);   // N*CH bf16

    // zero cnt + tailB in one shot (contiguous)
    hipMemsetAsync(cnt, 0, (N_NODES + 4096) * sizeof(int), stream);

    k_part<<<N_EDGES / 256, 256, 0, stream>>>(src, dst, tailB, P, cnt);
    k_rinv<<<(N_NODES + 255) / 256, 256, 0, stream>>>(cnt, rinv);
    k_gemm<<<N_NODES / 32, 256, 0, stream>>>(x, W, b, rinv, hs);
    k_spmm_b<<<NB, 256, 0, stream>>>(P, tailB, rinv, hs, out);
}

// Round 4
// 356.778 us; speedup vs baseline: 4.0273x; 4.0273x over previous
//
#include <hip/hip_runtime.h>
#include <hip/hip_bf16.h>

// GCN layer: out = D^-1/2 (A + I) D^-1/2 (x W^T + b)
// R4 pipeline:
//   0. memset tailB (3125 bucket tails only — no 100K-counter histogram)
//   1. k_part: 4 edges/thread; b=dst>>5; pos=atomicAdd(tailB[b]);
//              P[b*CAP+pos] = (src<<5)|(dst&31).  Write heads = 3125 lines
//              (200 KB, L2-resident) -> no write amplification (R2 k_fill: 105 MB).
//   2. k_deg:  per-bucket 32-bin LDS histogram of P -> rinv = rsqrt(deg+1)
//   3. k_gemm: hs = bf16( rinv[r] * (x W^T + b) )          (unchanged from R2)
//   4. k_spmm: per bucket: LDS counting-sort (exact segments), then R2's
//              measured-good 16-lane x uint4 x 4-unroll gather. out = rinv*acc.

#define N_NODES 100000
#define N_EDGES 1600000
#define CH 128
#define NB 3125          // buckets of 32 nodes; 3125*32 = 100000 exact
#define CAPB 704         // Poisson(512) + 8.5 sigma; overflow prob ~3e-12

__device__ inline unsigned short f2bf(float f) {          // RNE float->bf16
    unsigned u = __float_as_uint(f);
    u += 0x7fffu + ((u >> 16) & 1u);
    return (unsigned short)(u >> 16);
}
__device__ inline float bflo(unsigned u) { return __uint_as_float(u << 16); }
__device__ inline float bfhi(unsigned u) { return __uint_as_float(u & 0xffff0000u); }

// ---------------- bucket partition ----------------
__global__ __launch_bounds__(256) void k_part(const int* __restrict__ src,
                                              const int* __restrict__ dst,
                                              int* __restrict__ tailB,
                                              unsigned* __restrict__ P) {
    int tid = blockIdx.x * 256 + threadIdx.x;
    int base = tid * 4;
    if (base >= N_EDGES) return;          // N_EDGES % 4 == 0: never partial
    int4 sv = ((const int4*)src)[tid];
    int4 dv = ((const int4*)dst)[tid];
    int ss[4] = {sv.x, sv.y, sv.z, sv.w};
    int dd[4] = {dv.x, dv.y, dv.z, dv.w};
#pragma unroll
    for (int j = 0; j < 4; ++j) {
        int b = dd[j] >> 5;
        int pos = atomicAdd(&tailB[b], 1);
        if (pos < CAPB)
            P[(size_t)b * CAPB + pos] = ((unsigned)ss[j] << 5) | (unsigned)(dd[j] & 31);
    }
}

// ---------------- degrees -> rinv (per-bucket LDS histogram) ----------------
__global__ __launch_bounds__(64) void k_deg(const unsigned* __restrict__ P,
                                            const int* __restrict__ tailB,
                                            float* __restrict__ rinv) {
    __shared__ int bins[32];
    const int b = blockIdx.x;
    const int t = threadIdx.x;
    if (t < 32) bins[t] = 0;
    int nE = tailB[b]; if (nE > CAPB) nE = CAPB;
    __syncthreads();
    const unsigned* Pb = P + (size_t)b * CAPB;
    for (int i = t; i < nE; i += 64) atomicAdd(&bins[Pb[i] & 31], 1);
    __syncthreads();
    if (t < 32) rinv[b * 32 + t] = rsqrtf((float)(bins[t] + 1));
}

// ---------------- GEMM: hs = bf16( rinv * (x W^T + b) ) ----------------
// 32 rows x 128 cols per block, 256 threads, 4x4 micro-tile per thread.
__global__ __launch_bounds__(256) void k_gemm(const float* __restrict__ x,
                                              const float* __restrict__ W,
                                              const float* __restrict__ b,
                                              const float* __restrict__ rinv,
                                              unsigned short* __restrict__ hs) {
    __shared__ __align__(16) float xs[32][36];    // [row][kk]
    __shared__ __align__(16) float ws[32][132];   // [kk][o]
    const int t  = threadIdx.x;
    const int tx = t & 31;          // output cols o = 4*tx + c
    const int ty = t >> 5;          // rows r = ty + 8*i
    const int row0 = blockIdx.x * 32;

    float acc[4][4] = {};

    for (int k0 = 0; k0 < CH; k0 += 32) {
        {
            int r  = t >> 5;
            int kk = t & 31;
            for (int p = 0; p < 4; ++p) {
                int rr = r + p * 8;
                xs[rr][kk] = x[(size_t)(row0 + rr) * CH + k0 + kk];
            }
            int o = t >> 5;
            for (int p = 0; p < 16; ++p) {
                int oo = o + p * 8;
                ws[kk][oo] = W[(size_t)oo * CH + k0 + kk];
            }
        }
        __syncthreads();

        for (int k4 = 0; k4 < 32; k4 += 4) {
            float4 xv[4], wv[4];
            for (int i = 0; i < 4; ++i)
                xv[i] = *(const float4*)&xs[ty + 8 * i][k4];
            for (int j = 0; j < 4; ++j)
                wv[j] = *(const float4*)&ws[k4 + j][4 * tx];
            for (int i = 0; i < 4; ++i) {
                acc[i][0] += xv[i].x * wv[0].x; acc[i][1] += xv[i].x * wv[0].y;
                acc[i][2] += xv[i].x * wv[0].z; acc[i][3] += xv[i].x * wv[0].w;
                acc[i][0] += xv[i].y * wv[1].x; acc[i][1] += xv[i].y * wv[1].y;
                acc[i][2] += xv[i].y * wv[1].z; acc[i][3] += xv[i].y * wv[1].w;
                acc[i][0] += xv[i].z * wv[2].x; acc[i][1] += xv[i].z * wv[2].y;
                acc[i][2] += xv[i].z * wv[2].z; acc[i][3] += xv[i].z * wv[2].w;
                acc[i][0] += xv[i].w * wv[3].x; acc[i][1] += xv[i].w * wv[3].y;
                acc[i][2] += xv[i].w * wv[3].z; acc[i][3] += xv[i].w * wv[3].w;
            }
        }
        __syncthreads();
    }

    float4 bv = *(const float4*)&b[4 * tx];
    for (int i = 0; i < 4; ++i) {
        int r = row0 + ty + 8 * i;
        float ri = rinv[r];
        ushort4 o4;
        o4.x = f2bf(ri * (acc[i][0] + bv.x));
        o4.y = f2bf(ri * (acc[i][1] + bv.y));
        o4.z = f2bf(ri * (acc[i][2] + bv.z));
        o4.w = f2bf(ri * (acc[i][3] + bv.w));
        *(ushort4*)&hs[(size_t)r * CH + 4 * tx] = o4;
    }
}

// ---------------- bucketed SpMM: LDS sort + R2-style uint4 gather ----------------
#define ACC8(u)                                                            \
    do {                                                                   \
        acc[0] += bflo((u).x); acc[1] += bfhi((u).x);                      \
        acc[2] += bflo((u).y); acc[3] += bfhi((u).y);                      \
        acc[4] += bflo((u).z); acc[5] += bfhi((u).z);                      \
        acc[6] += bflo((u).w); acc[7] += bfhi((u).w);                      \
    } while (0)

__global__ __launch_bounds__(256) void k_spmm(const unsigned* __restrict__ P,
                                              const int* __restrict__ tailB,
                                              const float* __restrict__ rinv,
                                              const unsigned short* __restrict__ hs,
                                              float* __restrict__ out) {
    __shared__ int bins[32];
    __shared__ int binoff[33];
    __shared__ int cursor[32];
    __shared__ int srt[CAPB];
    const int b     = blockIdx.x;
    const int node0 = b << 5;
    const int t     = threadIdx.x;
    const unsigned* Pb = P + (size_t)b * CAPB;
    const uint4* hp = (const uint4*)hs;        // row s at hp[s*16 + lane]

    if (t < 32) bins[t] = 0;
    int nE = tailB[b]; if (nE > CAPB) nE = CAPB;
    __syncthreads();

    // pass 1: histogram by node-in-bucket
    for (int i = t; i < nE; i += 256) atomicAdd(&bins[Pb[i] & 31], 1);
    __syncthreads();

    // serial exclusive scan over 32 bins (one thread; ~trivial)
    if (t == 0) {
        int run = 0;
        for (int j = 0; j < 32; ++j) { binoff[j] = run; run += bins[j]; }
        binoff[32] = run;
    }
    __syncthreads();
    if (t < 32) cursor[t] = binoff[t];
    __syncthreads();

    // pass 2: scatter srcs into sorted order (P re-read is L2-hot)
    for (int i = t; i < nE; i += 256) {
        unsigned p = Pb[i];
        int pos = atomicAdd(&cursor[p & 31], 1);
        srt[pos] = (int)(p >> 5);
    }
    __syncthreads();

    // gather: 16 groups x 16 lanes; group handles nodes 2g, 2g+1
    const int grp  = t >> 4;
    const int lane = t & 15;
#pragma unroll
    for (int r = 0; r < 2; ++r) {
        const int nl   = grp * 2 + r;
        const int node = node0 + nl;
        float acc[8] = {};
        {   // self term
            uint4 u = hp[(size_t)node * 16 + lane];
            ACC8(u);
        }
        int e  = binoff[nl];
        int e1 = binoff[nl + 1];
        for (; e + 4 <= e1; e += 4) {
            int s0 = srt[e + 0];
            int s1 = srt[e + 1];
            int s2 = srt[e + 2];
            int s3 = srt[e + 3];
            uint4 u0 = hp[(size_t)s0 * 16 + lane];
            uint4 u1 = hp[(size_t)s1 * 16 + lane];
            uint4 u2 = hp[(size_t)s2 * 16 + lane];
            uint4 u3 = hp[(size_t)s3 * 16 + lane];
            ACC8(u0); ACC8(u1); ACC8(u2); ACC8(u3);
        }
        for (; e < e1; ++e) {
            uint4 u = hp[(size_t)srt[e] * 16 + lane];
            ACC8(u);
        }
        float ri = rinv[node];
        float4 o0, o1;
        o0.x = ri * acc[0]; o0.y = ri * acc[1]; o0.z = ri * acc[2]; o0.w = ri * acc[3];
        o1.x = ri * acc[4]; o1.y = ri * acc[5]; o1.z = ri * acc[6]; o1.w = ri * acc[7];
        *(float4*)&out[(size_t)node * CH + lane * 8]     = o0;
        *(float4*)&out[(size_t)node * CH + lane * 8 + 4] = o1;
    }
}

extern "C" void kernel_launch(void* const* d_in, const int* in_sizes, int n_in,
                              void* d_out, int out_size, void* d_ws, size_t ws_size,
                              hipStream_t stream) {
    const float* x  = (const float*)d_in[0];
    const int*   ei = (const int*)d_in[1];
    const float* W  = (const float*)d_in[2];
    const float* b  = (const float*)d_in[3];
    float* out = (float*)d_out;

    const int* src = ei;
    const int* dst = ei + N_EDGES;

    // workspace layout (4-byte units; hs offset 9,212,800 B — 16B aligned)
    int*      tailB = (int*)d_ws;                         // 3200 (NB used)
    float*    rinv  = (float*)(tailB + 3200);             // N
    unsigned* P     = (unsigned*)(rinv + N_NODES);        // NB*CAPB = 2,200,000
    unsigned short* hs = (unsigned short*)(P + (size_t)NB * CAPB);  // N*CH bf16

    hipMemsetAsync(tailB, 0, 3200 * sizeof(int), stream);

    k_part<<<(N_EDGES / 4 + 255) / 256, 256, 0, stream>>>(src, dst, tailB, P);
    k_deg<<<NB, 64, 0, stream>>>(P, tailB, rinv);
    k_gemm<<<N_NODES / 32, 256, 0, stream>>>(x, W, b, rinv, hs);
    k_spmm<<<NB, 256, 0, stream>>>(P, tailB, rinv, hs, out);
}

// Round 5
// 304.771 us; speedup vs baseline: 4.7145x; 1.1706x over previous
//
#include <hip/hip_runtime.h>
#include <hip/hip_bf16.h>

// GCN layer: out = D^-1/2 (A + I) D^-1/2 (x W^T + b)
// R5 pipeline:
//   0. memset tailB (3125 buckets x 8 XCD-private tails)
//   1. k_part: per edge: b=dst>>5, g=XCC_ID; pos=atomicAdd(tail[b*8+g]);
//              P[(b*8+g)*SUBCAP+pos] = (src<<5)|(dst&31).
//              Sub-buffers are 512 B (8 lines), 64B-aligned, written by ONE XCD
//              -> no cross-XCD line migration (R4's 82 MB WRITE / 144 us).
//   2. k_deg:  per-bucket 32-bin LDS histogram over the 8 sub-segments -> rinv
//   3. k_gemm: hs = bf16( rinv[r] * (x W^T + b) )            (unchanged)
//   4. k_spmm: per bucket: LDS counting-sort of the 8 sub-segments into exact
//              per-node runs, then the measured-good 16-lane uint4 x4 gather.

#define N_NODES 100000
#define N_EDGES 1600000
#define CH 128
#define NB 3125          // buckets of 32 nodes; 3125*32 = 100000 exact
#define SUBCAP 128       // per (bucket,XCD): Poisson(64) + 8 sigma; 512 B = 8 lines

__device__ inline unsigned short f2bf(float f) {          // RNE float->bf16
    unsigned u = __float_as_uint(f);
    u += 0x7fffu + ((u >> 16) & 1u);
    return (unsigned short)(u >> 16);
}
__device__ inline float bflo(unsigned u) { return __uint_as_float(u << 16); }
__device__ inline float bfhi(unsigned u) { return __uint_as_float(u & 0xffff0000u); }

__device__ inline int xcc_id() {
    int x;
    asm volatile("s_getreg_b32 %0, hwreg(HW_REG_XCC_ID)" : "=s"(x));
    return x & 7;
}

// ---------------- bucket partition (XCD-private sub-buffers) ----------------
__global__ __launch_bounds__(256) void k_part(const int* __restrict__ src,
                                              const int* __restrict__ dst,
                                              int* __restrict__ tailB,
                                              unsigned* __restrict__ P) {
    const int g = xcc_id();                   // wave-uniform
    int tid = blockIdx.x * 256 + threadIdx.x;
    if (tid * 4 >= N_EDGES) return;
    int4 sv = ((const int4*)src)[tid];
    int4 dv = ((const int4*)dst)[tid];
    int ss[4] = {sv.x, sv.y, sv.z, sv.w};
    int dd[4] = {dv.x, dv.y, dv.z, dv.w};
#pragma unroll
    for (int j = 0; j < 4; ++j) {
        int b = dd[j] >> 5;
        int pos = atomicAdd(&tailB[b * 8 + g], 1);
        if (pos < SUBCAP)
            P[((size_t)(b * 8 + g)) * SUBCAP + pos] =
                ((unsigned)ss[j] << 5) | (unsigned)(dd[j] & 31);
    }
}

// ---------------- degrees -> rinv (per-bucket LDS histogram) ----------------
__global__ __launch_bounds__(64) void k_deg(const unsigned* __restrict__ P,
                                            const int* __restrict__ tailB,
                                            float* __restrict__ rinv) {
    __shared__ int bins[32];
    __shared__ int subn[8];
    const int b = blockIdx.x;
    const int t = threadIdx.x;
    if (t < 32) bins[t] = 0;
    if (t < 8) {
        int n = tailB[b * 8 + t];
        subn[t] = (n > SUBCAP) ? SUBCAP : n;
    }
    __syncthreads();
    const unsigned* Pb = P + (size_t)b * 8 * SUBCAP;
    for (int g = 0; g < 8; ++g) {
        int n = subn[g];
        for (int i = t; i < n; i += 64)
            atomicAdd(&bins[Pb[g * SUBCAP + i] & 31], 1);
    }
    __syncthreads();
    if (t < 32) rinv[b * 32 + t] = rsqrtf((float)(bins[t] + 1));
}

// ---------------- GEMM: hs = bf16( rinv * (x W^T + b) ) ----------------
// 32 rows x 128 cols per block, 256 threads, 4x4 micro-tile per thread.
__global__ __launch_bounds__(256) void k_gemm(const float* __restrict__ x,
                                              const float* __restrict__ W,
                                              const float* __restrict__ b,
                                              const float* __restrict__ rinv,
                                              unsigned short* __restrict__ hs) {
    __shared__ __align__(16) float xs[32][36];    // [row][kk]
    __shared__ __align__(16) float ws[32][132];   // [kk][o]
    const int t  = threadIdx.x;
    const int tx = t & 31;          // output cols o = 4*tx + c
    const int ty = t >> 5;          // rows r = ty + 8*i
    const int row0 = blockIdx.x * 32;

    float acc[4][4] = {};

    for (int k0 = 0; k0 < CH; k0 += 32) {
        {
            int r  = t >> 5;
            int kk = t & 31;
            for (int p = 0; p < 4; ++p) {
                int rr = r + p * 8;
                xs[rr][kk] = x[(size_t)(row0 + rr) * CH + k0 + kk];
            }
            int o = t >> 5;
            for (int p = 0; p < 16; ++p) {
                int oo = o + p * 8;
                ws[kk][oo] = W[(size_t)oo * CH + k0 + kk];
            }
        }
        __syncthreads();

        for (int k4 = 0; k4 < 32; k4 += 4) {
            float4 xv[4], wv[4];
            for (int i = 0; i < 4; ++i)
                xv[i] = *(const float4*)&xs[ty + 8 * i][k4];
            for (int j = 0; j < 4; ++j)
                wv[j] = *(const float4*)&ws[k4 + j][4 * tx];
            for (int i = 0; i < 4; ++i) {
                acc[i][0] += xv[i].x * wv[0].x; acc[i][1] += xv[i].x * wv[0].y;
                acc[i][2] += xv[i].x * wv[0].z; acc[i][3] += xv[i].x * wv[0].w;
                acc[i][0] += xv[i].y * wv[1].x; acc[i][1] += xv[i].y * wv[1].y;
                acc[i][2] += xv[i].y * wv[1].z; acc[i][3] += xv[i].y * wv[1].w;
                acc[i][0] += xv[i].z * wv[2].x; acc[i][1] += xv[i].z * wv[2].y;
                acc[i][2] += xv[i].z * wv[2].z; acc[i][3] += xv[i].z * wv[2].w;
                acc[i][0] += xv[i].w * wv[3].x; acc[i][1] += xv[i].w * wv[3].y;
                acc[i][2] += xv[i].w * wv[3].z; acc[i][3] += xv[i].w * wv[3].w;
            }
        }
        __syncthreads();
    }

    float4 bv = *(const float4*)&b[4 * tx];
    for (int i = 0; i < 4; ++i) {
        int r = row0 + ty + 8 * i;
        float ri = rinv[r];
        ushort4 o4;
        o4.x = f2bf(ri * (acc[i][0] + bv.x));
        o4.y = f2bf(ri * (acc[i][1] + bv.y));
        o4.z = f2bf(ri * (acc[i][2] + bv.z));
        o4.w = f2bf(ri * (acc[i][3] + bv.w));
        *(ushort4*)&hs[(size_t)r * CH + 4 * tx] = o4;
    }
}

// ---------------- bucketed SpMM: LDS sort + uint4 gather ----------------
#define ACC8(u)                                                            \
    do {                                                                   \
        acc[0] += bflo((u).x); acc[1] += bfhi((u).x);                      \
        acc[2] += bflo((u).y); acc[3] += bfhi((u).y);                      \
        acc[4] += bflo((u).z); acc[5] += bfhi((u).z);                      \
        acc[6] += bflo((u).w); acc[7] += bfhi((u).w);                      \
    } while (0)

__global__ __launch_bounds__(256) void k_spmm(const unsigned* __restrict__ P,
                                              const int* __restrict__ tailB,
                                              const float* __restrict__ rinv,
                                              const unsigned short* __restrict__ hs,
                                              float* __restrict__ out) {
    __shared__ int bins[32];
    __shared__ int binoff[33];
    __shared__ int cursor[32];
    __shared__ int subn[8];
    __shared__ int srt[8 * SUBCAP];
    const int b     = blockIdx.x;
    const int node0 = b << 5;
    const int t     = threadIdx.x;
    const unsigned* Pb = P + (size_t)b * 8 * SUBCAP;
    const uint4* hp = (const uint4*)hs;        // row s at hp[s*16 + lane]

    if (t < 32) bins[t] = 0;
    if (t < 8) {
        int n = tailB[b * 8 + t];
        subn[t] = (n > SUBCAP) ? SUBCAP : n;
    }
    __syncthreads();

    // pass 1: histogram by node-in-bucket over the 8 sub-segments
    for (int g = 0; g < 8; ++g) {
        int n = subn[g];
        for (int i = t; i < n; i += 256)
            atomicAdd(&bins[Pb[g * SUBCAP + i] & 31], 1);
    }
    __syncthreads();

    if (t == 0) {
        int run = 0;
        for (int j = 0; j < 32; ++j) { binoff[j] = run; run += bins[j]; }
        binoff[32] = run;
    }
    __syncthreads();
    if (t < 32) cursor[t] = binoff[t];
    __syncthreads();

    // pass 2: scatter srcs into sorted order (P re-read is L2-hot)
    for (int g = 0; g < 8; ++g) {
        int n = subn[g];
        for (int i = t; i < n; i += 256) {
            unsigned p = Pb[g * SUBCAP + i];
            int pos = atomicAdd(&cursor[p & 31], 1);
            srt[pos] = (int)(p >> 5);
        }
    }
    __syncthreads();

    // gather: 16 groups x 16 lanes; group handles nodes 2g, 2g+1
    const int grp  = t >> 4;
    const int lane = t & 15;
#pragma unroll
    for (int r = 0; r < 2; ++r) {
        const int nl   = grp * 2 + r;
        const int node = node0 + nl;
        float acc[8] = {};
        {   // self term
            uint4 u = hp[(size_t)node * 16 + lane];
            ACC8(u);
        }
        int e  = binoff[nl];
        int e1 = binoff[nl + 1];
        for (; e + 4 <= e1; e += 4) {
            int s0 = srt[e + 0];
            int s1 = srt[e + 1];
            int s2 = srt[e + 2];
            int s3 = srt[e + 3];
            uint4 u0 = hp[(size_t)s0 * 16 + lane];
            uint4 u1 = hp[(size_t)s1 * 16 + lane];
            uint4 u2 = hp[(size_t)s2 * 16 + lane];
            uint4 u3 = hp[(size_t)s3 * 16 + lane];
            ACC8(u0); ACC8(u1); ACC8(u2); ACC8(u3);
        }
        for (; e < e1; ++e) {
            uint4 u = hp[(size_t)srt[e] * 16 + lane];
            ACC8(u);
        }
        float ri = rinv[node];
        float4 o0, o1;
        o0.x = ri * acc[0]; o0.y = ri * acc[1]; o0.z = ri * acc[2]; o0.w = ri * acc[3];
        o1.x = ri * acc[4]; o1.y = ri * acc[5]; o1.z = ri * acc[6]; o1.w = ri * acc[7];
        *(float4*)&out[(size_t)node * CH + lane * 8]     = o0;
        *(float4*)&out[(size_t)node * CH + lane * 8 + 4] = o1;
    }
}

extern "C" void kernel_launch(void* const* d_in, const int* in_sizes, int n_in,
                              void* d_out, int out_size, void* d_ws, size_t ws_size,
                              hipStream_t stream) {
    const float* x  = (const float*)d_in[0];
    const int*   ei = (const int*)d_in[1];
    const float* W  = (const float*)d_in[2];
    const float* b  = (const float*)d_in[3];
    float* out = (float*)d_out;

    const int* src = ei;
    const int* dst = ei + N_EDGES;

    // workspace layout (4-byte units):
    //   tailB: 25600 slots (25000 used; padded so P is 64B-aligned)
    //   rinv : 100000
    //   P    : NB*8*SUBCAP = 3,200,000   (starts at byte 502,400 — 64B aligned)
    //   hs   : N*CH bf16                 (starts at byte 13,302,400 — 64B aligned)
    int*      tailB = (int*)d_ws;
    float*    rinv  = (float*)(tailB + 25600);
    unsigned* P     = (unsigned*)(rinv + N_NODES);
    unsigned short* hs = (unsigned short*)(P + (size_t)NB * 8 * SUBCAP);

    hipMemsetAsync(tailB, 0, 25000 * sizeof(int), stream);

    k_part<<<(N_EDGES / 4 + 255) / 256, 256, 0, stream>>>(src, dst, tailB, P);
    k_deg<<<NB, 64, 0, stream>>>(P, tailB, rinv);
    k_gemm<<<N_NODES / 32, 256, 0, stream>>>(x, W, b, rinv, hs);
    k_spmm<<<NB, 256, 0, stream>>>(P, tailB, rinv, hs, out);
}

// Round 6
// 250.403 us; speedup vs baseline: 5.7381x; 1.2171x over previous
//
#include <hip/hip_runtime.h>
#include <hip/hip_bf16.h>

// GCN layer: out = D^-1/2 (A + I) D^-1/2 (x W^T + b)
// R6 pipeline — two-level counting sort with ONLY coalesced-run global writes
// (R5 lesson: gfx950 TCC does not write-allocate scattered 4B stores; each
//  costs a ~32B HBM sector write -> 58 MB. Runs written by consecutive lanes
//  coalesce into full lines before L2.)
//   1. k_sortA: 2048 edges/block -> LDS counting sort into 49 coarse buckets
//               (2048 nodes); 49 global-atomic run reservations/block; linear
//               run writes. pack = (src<<11)|(dst&2047).
//   2. k_sortB: per (coarse,chunk): re-bin into 64-node fine buckets (1563);
//               same LDS sort + run reservation; pack = (src<<6)|(dst&63).
//   3. k_deg:   per fine bucket: 64-bin LDS hist -> rinv = rsqrt(deg+1)
//   4. k_gemm:  hs = bf16( rinv[r] * (x W^T + b) )        (unchanged)
//   5. k_spmm:  per fine bucket: LDS counting sort -> exact per-node runs,
//               then 16-lane uint4 x4-unroll gather.    out = rinv*acc.

#define N_NODES 100000
#define N_EDGES 1600000
#define CH 128
#define NC 49            // coarse buckets of 2048 nodes
#define CAPC 34816       // 17*2048; mean 32768 + 11 sigma
#define NCHUNK 17
#define NFB 1563         // fine buckets of 64 nodes (1563*64 = 100032)
#define FCAP 1280        // mean 1024 + 8 sigma

__device__ inline unsigned short f2bf(float f) {          // RNE float->bf16
    unsigned u = __float_as_uint(f);
    u += 0x7fffu + ((u >> 16) & 1u);
    return (unsigned short)(u >> 16);
}
__device__ inline float bflo(unsigned u) { return __uint_as_float(u << 16); }
__device__ inline float bfhi(unsigned u) { return __uint_as_float(u & 0xffff0000u); }

// ---------------- phase A: sort into 49 coarse buckets ----------------
__global__ __launch_bounds__(256) void k_sortA(const int* __restrict__ src,
                                               const int* __restrict__ dst,
                                               int* __restrict__ ctail,
                                               unsigned* __restrict__ E1) {
    __shared__ int hist[NC];
    __shared__ int boff[NC + 1];
    __shared__ int cur[NC];
    __shared__ int gb[NC];
    __shared__ unsigned stage[2048];
    const int t    = threadIdx.x;
    const int base = blockIdx.x * 2048;
    const int n    = min(2048, N_EDGES - base);   // 2048, or 512 in last block

    if (t < NC) hist[t] = 0;
    __syncthreads();

    int s[8], d[8];
#pragma unroll
    for (int h = 0; h < 2; ++h) {
        int idx = h * 1024 + 4 * t;
        if (idx < n) {                    // n in {512,2048}: int4 never straddles
            int4 sv = *(const int4*)&src[base + idx];
            int4 dv = *(const int4*)&dst[base + idx];
            s[4*h+0] = sv.x; s[4*h+1] = sv.y; s[4*h+2] = sv.z; s[4*h+3] = sv.w;
            d[4*h+0] = dv.x; d[4*h+1] = dv.y; d[4*h+2] = dv.z; d[4*h+3] = dv.w;
        } else {
            d[4*h+0] = d[4*h+1] = d[4*h+2] = d[4*h+3] = -1;
            s[4*h+0] = s[4*h+1] = s[4*h+2] = s[4*h+3] = 0;
        }
    }
#pragma unroll
    for (int j = 0; j < 8; ++j)
        if (d[j] >= 0) atomicAdd(&hist[d[j] >> 11], 1);
    __syncthreads();

    if (t < NC) gb[t] = atomicAdd(&ctail[t], hist[t]);
    if (t == 0) {
        int run = 0;
        for (int k = 0; k < NC; ++k) { boff[k] = run; run += hist[k]; }
        boff[NC] = run;
    }
    __syncthreads();
    if (t < NC) cur[t] = boff[t];
    __syncthreads();

#pragma unroll
    for (int j = 0; j < 8; ++j)
        if (d[j] >= 0) {
            int k = d[j] >> 11;
            int pos = atomicAdd(&cur[k], 1);
            stage[pos] = ((unsigned)s[j] << 11) | (unsigned)(d[j] & 2047);
        }
    __syncthreads();

    const int tot = boff[NC];
    for (int i = t; i < tot; i += 256) {
        int lo = 0, hi = NC;              // invariant: boff[lo] <= i < boff[hi]
#pragma unroll
        for (int it = 0; it < 6; ++it) {
            int mid = (lo + hi) >> 1;
            bool c = (boff[mid] <= i);
            lo = c ? mid : lo;
            hi = c ? hi : mid;
        }
        int p = gb[lo] + (i - boff[lo]);
        if (p < CAPC) E1[(size_t)lo * CAPC + p] = stage[i];
    }
}

// ---------------- phase B: re-bin coarse -> 64-node fine buckets ----------------
__global__ __launch_bounds__(256) void k_sortB(const unsigned* __restrict__ E1,
                                               const int* __restrict__ ctail,
                                               int* __restrict__ ftail,
                                               unsigned* __restrict__ E2) {
    __shared__ int hist[32];
    __shared__ int boff[33];
    __shared__ int cur[32];
    __shared__ int gb[32];
    __shared__ unsigned stage[2048];
    const int cb = blockIdx.x / NCHUNK;
    const int ch = blockIdx.x % NCHUNK;
    const int t  = threadIdx.x;
    int cnt = ctail[cb]; if (cnt > CAPC) cnt = CAPC;
    const int begin = ch * 2048;
    int n = cnt - begin;
    if (n <= 0) return;                   // uniform across block
    if (n > 2048) n = 2048;
    const unsigned* e1 = E1 + (size_t)cb * CAPC + begin;

    if (t < 32) hist[t] = 0;
    __syncthreads();

    for (int i = t; i < n; i += 256)
        atomicAdd(&hist[(e1[i] >> 6) & 31], 1);
    __syncthreads();

    if (t < 32) gb[t] = atomicAdd(&ftail[cb * 32 + t], hist[t]);
    if (t == 0) {
        int run = 0;
        for (int k = 0; k < 32; ++k) { boff[k] = run; run += hist[k]; }
        boff[32] = run;
    }
    __syncthreads();
    if (t < 32) cur[t] = boff[t];
    __syncthreads();

    for (int i = t; i < n; i += 256) {
        unsigned v = e1[i];
        int k = (v >> 6) & 31;
        int pos = atomicAdd(&cur[k], 1);
        stage[pos] = ((v >> 11) << 6) | (v & 63);   // (src<<6)|(dst&63)
    }
    __syncthreads();

    const int tot = boff[32];
    for (int i = t; i < tot; i += 256) {
        int lo = 0, hi = 32;
#pragma unroll
        for (int it = 0; it < 5; ++it) {
            int mid = (lo + hi) >> 1;
            bool c = (boff[mid] <= i);
            lo = c ? mid : lo;
            hi = c ? hi : mid;
        }
        int p = gb[lo] + (i - boff[lo]);
        int fb = cb * 32 + lo;
        if (p < FCAP) E2[(size_t)fb * FCAP + p] = stage[i];
    }
}

// ---------------- degrees -> rinv ----------------
__global__ __launch_bounds__(256) void k_deg(const unsigned* __restrict__ E2,
                                             const int* __restrict__ ftail,
                                             float* __restrict__ rinv) {
    __shared__ int bins[64];
    const int fb = blockIdx.x;
    const int t  = threadIdx.x;
    if (t < 64) bins[t] = 0;
    int n = ftail[fb]; if (n > FCAP) n = FCAP;
    __syncthreads();
    const unsigned* e2 = E2 + (size_t)fb * FCAP;
    for (int i = t; i < n; i += 256) atomicAdd(&bins[e2[i] & 63], 1);
    __syncthreads();
    if (t < 64) {
        int node = fb * 64 + t;
        if (node < N_NODES) rinv[node] = rsqrtf((float)(bins[t] + 1));
    }
}

// ---------------- GEMM: hs = bf16( rinv * (x W^T + b) ) ----------------
// 32 rows x 128 cols per block, 256 threads, 4x4 micro-tile per thread.
__global__ __launch_bounds__(256) void k_gemm(const float* __restrict__ x,
                                              const float* __restrict__ W,
                                              const float* __restrict__ b,
                                              const float* __restrict__ rinv,
                                              unsigned short* __restrict__ hs) {
    __shared__ __align__(16) float xs[32][36];    // [row][kk]
    __shared__ __align__(16) float ws[32][132];   // [kk][o]
    const int t  = threadIdx.x;
    const int tx = t & 31;          // output cols o = 4*tx + c
    const int ty = t >> 5;          // rows r = ty + 8*i
    const int row0 = blockIdx.x * 32;

    float acc[4][4] = {};

    for (int k0 = 0; k0 < CH; k0 += 32) {
        {
            int r  = t >> 5;
            int kk = t & 31;
            for (int p = 0; p < 4; ++p) {
                int rr = r + p * 8;
                xs[rr][kk] = x[(size_t)(row0 + rr) * CH + k0 + kk];
            }
            int o = t >> 5;
            for (int p = 0; p < 16; ++p) {
                int oo = o + p * 8;
                ws[kk][oo] = W[(size_t)oo * CH + k0 + kk];
            }
        }
        __syncthreads();

        for (int k4 = 0; k4 < 32; k4 += 4) {
            float4 xv[4], wv[4];
            for (int i = 0; i < 4; ++i)
                xv[i] = *(const float4*)&xs[ty + 8 * i][k4];
            for (int j = 0; j < 4; ++j)
                wv[j] = *(const float4*)&ws[k4 + j][4 * tx];
            for (int i = 0; i < 4; ++i) {
                acc[i][0] += xv[i].x * wv[0].x; acc[i][1] += xv[i].x * wv[0].y;
                acc[i][2] += xv[i].x * wv[0].z; acc[i][3] += xv[i].x * wv[0].w;
                acc[i][0] += xv[i].y * wv[1].x; acc[i][1] += xv[i].y * wv[1].y;
                acc[i][2] += xv[i].y * wv[1].z; acc[i][3] += xv[i].y * wv[1].w;
                acc[i][0] += xv[i].z * wv[2].x; acc[i][1] += xv[i].z * wv[2].y;
                acc[i][2] += xv[i].z * wv[2].z; acc[i][3] += xv[i].z * wv[2].w;
                acc[i][0] += xv[i].w * wv[3].x; acc[i][1] += xv[i].w * wv[3].y;
                acc[i][2] += xv[i].w * wv[3].z; acc[i][3] += xv[i].w * wv[3].w;
            }
        }
        __syncthreads();
    }

    float4 bv = *(const float4*)&b[4 * tx];
    for (int i = 0; i < 4; ++i) {
        int r = row0 + ty + 8 * i;
        float ri = rinv[r];
        ushort4 o4;
        o4.x = f2bf(ri * (acc[i][0] + bv.x));
        o4.y = f2bf(ri * (acc[i][1] + bv.y));
        o4.z = f2bf(ri * (acc[i][2] + bv.z));
        o4.w = f2bf(ri * (acc[i][3] + bv.w));
        *(ushort4*)&hs[(size_t)r * CH + 4 * tx] = o4;
    }
}

// ---------------- fine-bucket SpMM: LDS sort + uint4 gather ----------------
#define ACC8(u)                                                            \
    do {                                                                   \
        acc[0] += bflo((u).x); acc[1] += bfhi((u).x);                      \
        acc[2] += bflo((u).y); acc[3] += bfhi((u).y);                      \
        acc[4] += bflo((u).z); acc[5] += bfhi((u).z);                      \
        acc[6] += bflo((u).w); acc[7] += bfhi((u).w);                      \
    } while (0)

__global__ __launch_bounds__(256) void k_spmm(const unsigned* __restrict__ E2,
                                              const int* __restrict__ ftail,
                                              const float* __restrict__ rinv,
                                              const unsigned short* __restrict__ hs,
                                              float* __restrict__ out) {
    __shared__ int bins[64];
    __shared__ int boff[65];
    __shared__ int cur[64];
    __shared__ int srt[FCAP];
    const int fb    = blockIdx.x;
    const int node0 = fb * 64;
    const int t     = threadIdx.x;
    const unsigned* e2 = E2 + (size_t)fb * FCAP;
    const uint4* hp = (const uint4*)hs;        // row s at hp[s*16 + lane]

    if (t < 64) bins[t] = 0;
    int n = ftail[fb]; if (n > FCAP) n = FCAP;
    __syncthreads();

    for (int i = t; i < n; i += 256) atomicAdd(&bins[e2[i] & 63], 1);
    __syncthreads();

    if (t == 0) {
        int run = 0;
        for (int k = 0; k < 64; ++k) { boff[k] = run; run += bins[k]; }
        boff[64] = run;
    }
    __syncthreads();
    if (t < 64) cur[t] = boff[t];
    __syncthreads();

    for (int i = t; i < n; i += 256) {
        unsigned v = e2[i];
        int pos = atomicAdd(&cur[v & 63], 1);
        srt[pos] = (int)(v >> 6);
    }
    __syncthreads();

    // gather: 16 groups x 16 lanes; group g handles nodes 4g..4g+3
    const int grp  = t >> 4;
    const int lane = t & 15;
#pragma unroll
    for (int r = 0; r < 4; ++r) {
        const int nl   = grp * 4 + r;
        const int node = node0 + nl;
        if (node >= N_NODES) continue;
        float acc[8] = {};
        {   // self term
            uint4 u = hp[(size_t)node * 16 + lane];
            ACC8(u);
        }
        int e  = boff[nl];
        int e1 = boff[nl + 1];
        for (; e + 4 <= e1; e += 4) {
            int s0 = srt[e + 0];
            int s1 = srt[e + 1];
            int s2 = srt[e + 2];
            int s3 = srt[e + 3];
            uint4 u0 = hp[(size_t)s0 * 16 + lane];
            uint4 u1 = hp[(size_t)s1 * 16 + lane];
            uint4 u2 = hp[(size_t)s2 * 16 + lane];
            uint4 u3 = hp[(size_t)s3 * 16 + lane];
            ACC8(u0); ACC8(u1); ACC8(u2); ACC8(u3);
        }
        for (; e < e1; ++e) {
            uint4 u = hp[(size_t)srt[e] * 16 + lane];
            ACC8(u);
        }
        float ri = rinv[node];
        float4 o0, o1;
        o0.x = ri * acc[0]; o0.y = ri * acc[1]; o0.z = ri * acc[2]; o0.w = ri * acc[3];
        o1.x = ri * acc[4]; o1.y = ri * acc[5]; o1.z = ri * acc[6]; o1.w = ri * acc[7];
        *(float4*)&out[(size_t)node * CH + lane * 8]     = o0;
        *(float4*)&out[(size_t)node * CH + lane * 8 + 4] = o1;
    }
}

extern "C" void kernel_launch(void* const* d_in, const int* in_sizes, int n_in,
                              void* d_out, int out_size, void* d_ws, size_t ws_size,
                              hipStream_t stream) {
    const float* x  = (const float*)d_in[0];
    const int*   ei = (const int*)d_in[1];
    const float* W  = (const float*)d_in[2];
    const float* b  = (const float*)d_in[3];
    float* out = (float*)d_out;

    const int* src = ei;
    const int* dst = ei + N_EDGES;

    // workspace layout (4-byte units; all region starts 16B-aligned):
    //   ctail : 64    (49 used)
    //   ftail : 1600  (1568 used)
    //   rinv  : 100000
    //   E1    : 49*34816   = 1,705,984
    //   E2    : 1563*1280  = 2,000,640
    //   hs    : N*CH bf16  = 12,800,000 shorts
    int*      ctail = (int*)d_ws;
    int*      ftail = ctail + 64;
    float*    rinv  = (float*)(ftail + 1600);
    unsigned* E1    = (unsigned*)(rinv + N_NODES);
    unsigned* E2    = E1 + (size_t)NC * CAPC;
    unsigned short* hs = (unsigned short*)(E2 + (size_t)NFB * FCAP);

    hipMemsetAsync(ctail, 0, (64 + 1600) * sizeof(int), stream);

    k_sortA<<<(N_EDGES + 2047) / 2048, 256, 0, stream>>>(src, dst, ctail, E1);
    k_sortB<<<NC * NCHUNK, 256, 0, stream>>>(E1, ctail, ftail, E2);
    k_deg<<<NFB, 256, 0, stream>>>(E2, ftail, rinv);
    k_gemm<<<N_NODES / 32, 256, 0, stream>>>(x, W, b, rinv, hs);
    k_spmm<<<NFB, 256, 0, stream>>>(E2, ftail, rinv, hs, out);
}